// Round 8
// baseline (190.839 us; speedup 1.0000x reference)
//
#include <hip/hip_runtime.h>
#include <hip/hip_fp16.h>

#define F_IN 128
#define F_OUT 32
#define PBLK 256   // phase-1 partition blocks (proven locality at 256)
#define BSH 7      // 128 nodes per bucket
#define BMSK 127
#define MAXB 1024  // max buckets supported (N <= 131072)

// ============ L1: k_hist — per-partition bucket histogram -> M[b][p] ======
__global__ __launch_bounds__(256) void k_hist(const int* __restrict__ col,
                                              int* __restrict__ M, int E_, int NB) {
    __shared__ int h[MAXB];
    int p = blockIdx.x, t = threadIdx.x;
    for (int b = t; b < NB; b += 256) h[b] = 0;
    __syncthreads();
    int epb = (E_ + PBLK - 1) / PBLK;
    int e0 = p * epb, e1 = min(e0 + epb, E_);
    for (int e = e0 + t; e < e1; e += 256)
        atomicAdd(&h[col[e] >> BSH], 1);            // LDS atomic
    __syncthreads();
    for (int b = t; b < NB; b += 256) M[(size_t)b * PBLK + p] = h[b];
}

// ============ L2: k_scanA — per-bucket exclusive scan over partitions =====
// grid = NB blocks; M row-contiguous (coalesced read/write).
__global__ __launch_bounds__(256) void k_scanA(int* __restrict__ M,
                                               int* __restrict__ total, int NB) {
    __shared__ int sd[256];
    int b = blockIdx.x, t = threadIdx.x;
    int v = M[(size_t)b * PBLK + t];
    sd[t] = v;
    __syncthreads();
    for (int o = 1; o < 256; o <<= 1) {
        int u = (t >= o) ? sd[t - o] : 0;
        __syncthreads();
        sd[t] += u;
        __syncthreads();
    }
    M[(size_t)b * PBLK + t] = sd[t] - v;
    if (t == 255) total[b] = sd[255];
}

// ============ L3: k_scat1 — redundant base-scan + partition scatter =======
// grid = PBLK blocks. Block 0 publishes base[] for later kernels.
__global__ __launch_bounds__(256) void k_scat1(
    const int* __restrict__ ei, const int* __restrict__ M,
    const int* __restrict__ total, int* __restrict__ base,
    unsigned* __restrict__ staging, int E_, int NB) {
    __shared__ int scur[MAXB];
    __shared__ int sd[256];
    int p = blockIdx.x, t = threadIdx.x;
    // redundant exclusive scan of total[0..NB) (NB <= 1024, C <= 4)
    int C = (NB + 255) >> 8;
    int vals[4];
    int run = 0;
    for (int j = 0; j < C; ++j) {
        int b = t * C + j;
        int v = (b < NB) ? total[b] : 0;
        vals[j] = run;
        run += v;
    }
    int tsum = run;
    sd[t] = tsum;
    __syncthreads();
    for (int o = 1; o < 256; o <<= 1) {
        int u = (t >= o) ? sd[t - o] : 0;
        __syncthreads();
        sd[t] += u;
        __syncthreads();
    }
    int cb = sd[t] - tsum;
    for (int j = 0; j < C; ++j) {
        int b = t * C + j;
        if (b < NB) {
            int sb = cb + vals[j];
            scur[b] = sb + M[(size_t)b * PBLK + p];
            if (p == 0) base[b] = sb;
        }
    }
    if (p == 0 && t == 255) base[NB] = sd[255];  // == E
    __syncthreads();
    int epb = (E_ + PBLK - 1) / PBLK;
    int e0 = p * epb, e1 = min(e0 + epb, E_);
    const int* col = ei + E_;
    for (int e = e0 + t; e < e1; e += 256) {
        int c = col[e];
        int r = ei[e];
        int pos = atomicAdd(&scur[c >> BSH], 1);   // LDS atomic (block-private)
        staging[pos] = ((unsigned)r << BSH) | (unsigned)(c & BMSK);
    }
}

// ============ L4: k_sort2 — per-bucket sort + deg/dis/cursor ==============
// grid = NB blocks (782 at N=100K -> ~3 blocks/CU).
__global__ __launch_bounds__(256) void k_sort2(
    const unsigned* __restrict__ staging, const int* __restrict__ base,
    int* __restrict__ esr, float* __restrict__ dis,
    int* __restrict__ cursor, int Nn, int E_, int NB) {
    __shared__ int hist[256];
    __shared__ int sd[256];
    __shared__ int lcur[256];
    int b = blockIdx.x, t = threadIdx.x;
    int nb0 = b << BSH;
    int nc = min(1 << BSH, Nn - nb0);
    hist[t] = 0;
    __syncthreads();
    int s0 = base[b], s1 = base[b + 1];
    for (int j = s0 + t; j < s1; j += 256)
        atomicAdd(&hist[staging[j] & BMSK], 1);    // LDS atomic
    __syncthreads();
    int h = hist[t];
    if (t < nc) dis[nb0 + t] = rsqrtf((float)h + 1.0f);
    sd[t] = h;
    __syncthreads();
    for (int o = 1; o < 256; o <<= 1) {
        int u = (t >= o) ? sd[t - o] : 0;
        __syncthreads();
        sd[t] += u;
        __syncthreads();
    }
    int excl = sd[t] - h;
    if (t < nc) cursor[nb0 + t] = s0 + excl;
    if (b == NB - 1 && t == 0) cursor[Nn] = E_;
    lcur[t] = s0 + excl;
    __syncthreads();
    for (int j = s0 + t; j < s1; j += 256) {
        unsigned v = staging[j];
        int pp = atomicAdd(&lcur[v & BMSK], 1);    // LDS atomic
        esr[pp] = (int)(v >> BSH);
    }
}

// ============ L5: k1_xw — fused specnorm + matmul, xwh = f16(xW^T * dis) ==
__global__ __launch_bounds__(256) void k1_xw(
    const float* __restrict__ x, const float* __restrict__ W,
    const float* __restrict__ u, const float* __restrict__ dis,
    __half* __restrict__ xwh, int Nn) {
    __shared__ float xs[128 * 65];
    __shared__ float wt[128 * 32];
    __shared__ float sv[F_IN];
    __shared__ float sr[F_IN];
    __shared__ float ssc;
    int t = threadIdx.x;

    // ---- redundant spectral norm (per block; W is 16 KB, L2-hot) ----
    if (t < F_IN) {
        float a = 0.f;
        for (int i = 0; i < F_OUT; ++i) a += W[i * F_IN + t] * u[i];
        sv[t] = a; sr[t] = a * a;
    }
    __syncthreads();
    for (int o = 64; o > 0; o >>= 1) {
        if (t < o) sr[t] += sr[t + o];
        __syncthreads();
    }
    if (t == 0) ssc = 1.0f / fmaxf(sqrtf(sr[0]), 1e-12f);
    __syncthreads();
    if (t < F_IN) sv[t] *= ssc;
    __syncthreads();
    if (t < F_OUT) {
        float a = 0.f;
        for (int j = 0; j < F_IN; ++j) a += W[t * F_IN + j] * sv[j];
        sr[t] = a * a;
    }
    __syncthreads();
    for (int o = 16; o > 0; o >>= 1) {
        if (t < o) sr[t] += sr[t + o];
        __syncthreads();
    }
    if (t == 0) ssc = 1.0f / fmaxf(sqrtf(sr[0]), 1e-30f);  // 1/sigma
    __syncthreads();
    float is = ssc;

    // ---- matmul tile ----
    int rbase = blockIdx.x * 128;
    {   // stage W transposed, scaled by 1/sigma
        int f = t >> 3;
        int kb = 16 * (t & 7);
        const float4* wrow = (const float4*)(W + (size_t)f * F_IN + kb);
#pragma unroll
        for (int j = 0; j < 4; ++j) {
            float4 w = wrow[j];
            int k = kb + 4 * j;
            wt[(k + 0) * 32 + f] = w.x * is;
            wt[(k + 1) * 32 + f] = w.y * is;
            wt[(k + 2) * 32 + f] = w.z * is;
            wt[(k + 3) * 32 + f] = w.w * is;
        }
    }

    int r0 = (t >> 3) * 4;
    int f0 = (t & 7) * 4;
    float4 acc0 = {0, 0, 0, 0}, acc1 = {0, 0, 0, 0};
    float4 acc2 = {0, 0, 0, 0}, acc3 = {0, 0, 0, 0};
    const float4* wt4 = (const float4*)wt;
    int fq = f0 >> 2;

    for (int kc = 0; kc < 2; ++kc) {
        __syncthreads();
        {
            int rr = t >> 4;
            int k0 = 4 * (t & 15);
#pragma unroll
            for (int pi = 0; pi < 8; ++pi) {
                int r = pi * 16 + rr;
                int grow = rbase + r;
                if (grow >= Nn) grow = Nn - 1;
                float4 v = *(const float4*)(x + (size_t)grow * F_IN + kc * 64 + k0);
                xs[r * 65 + k0 + 0] = v.x;
                xs[r * 65 + k0 + 1] = v.y;
                xs[r * 65 + k0 + 2] = v.z;
                xs[r * 65 + k0 + 3] = v.w;
            }
        }
        __syncthreads();
#pragma unroll 4
        for (int kk = 0; kk < 64; ++kk) {
            int k = kc * 64 + kk;
            float4 w = wt4[k * 8 + fq];
            float x0 = xs[(r0 + 0) * 65 + kk];
            float x1 = xs[(r0 + 1) * 65 + kk];
            float x2 = xs[(r0 + 2) * 65 + kk];
            float x3 = xs[(r0 + 3) * 65 + kk];
            acc0.x += x0 * w.x; acc0.y += x0 * w.y; acc0.z += x0 * w.z; acc0.w += x0 * w.w;
            acc1.x += x1 * w.x; acc1.y += x1 * w.y; acc1.z += x1 * w.z; acc1.w += x1 * w.w;
            acc2.x += x2 * w.x; acc2.y += x2 * w.y; acc2.z += x2 * w.z; acc2.w += x2 * w.w;
            acc3.x += x3 * w.x; acc3.y += x3 * w.y; acc3.z += x3 * w.z; acc3.w += x3 * w.w;
        }
    }
    int g0 = rbase + r0;
#pragma unroll
    for (int q = 0; q < 4; ++q) {
        int g = g0 + q;
        if (g < Nn) {
            float d = dis[g];
            float4 a = (q == 0) ? acc0 : (q == 1) ? acc1 : (q == 2) ? acc2 : acc3;
            ushort4 s;
            s.x = __half_as_ushort(__float2half(a.x * d));
            s.y = __half_as_ushort(__float2half(a.y * d));
            s.z = __half_as_ushort(__float2half(a.z * d));
            s.w = __half_as_ushort(__float2half(a.w * d));
            *(ushort4*)(xwh + (size_t)g * F_OUT + f0) = s;
        }
    }
}

// ============ L6: k_gather — 16-lane groups, half2, scaled xwh ============
__global__ __launch_bounds__(256) void k_gather(
    const int* __restrict__ esr, const int* __restrict__ cursor,
    const __half* __restrict__ xws, const float* __restrict__ dis,
    const float* __restrict__ bias, const float* __restrict__ pa,
    float* __restrict__ out, int Nn) {
    int t = threadIdx.x;
    int node = blockIdx.x * 16 + (t >> 4);
    if (node >= Nn) return;
    int f2 = t & 15;  // feature pair 2*f2, 2*f2+1
    int start = cursor[node], end = cursor[node + 1];
    float accx = 0.f, accy = 0.f;
    for (int j0 = start; j0 < end; j0 += 16) {
        int idx = j0 + f2;
        int rf = (idx < end) ? esr[idx] : 0;
        int m = end - j0;
        if (m > 16) m = 16;
        int i = 0;
        for (; i + 4 <= m; i += 4) {
            int r0 = __shfl(rf, i + 0, 16);
            int r1 = __shfl(rf, i + 1, 16);
            int r2 = __shfl(rf, i + 2, 16);
            int r3 = __shfl(rf, i + 3, 16);
            float2 a0 = __half22float2(*((const __half2*)(xws + (size_t)r0 * F_OUT) + f2));
            float2 a1 = __half22float2(*((const __half2*)(xws + (size_t)r1 * F_OUT) + f2));
            float2 a2 = __half22float2(*((const __half2*)(xws + (size_t)r2 * F_OUT) + f2));
            float2 a3 = __half22float2(*((const __half2*)(xws + (size_t)r3 * F_OUT) + f2));
            accx += a0.x + a1.x + a2.x + a3.x;
            accy += a0.y + a1.y + a2.y + a3.y;
        }
        for (; i < m; ++i) {
            int r = __shfl(rf, i, 16);
            float2 a = __half22float2(*((const __half2*)(xws + (size_t)r * F_OUT) + f2));
            accx += a.x;
            accy += a.y;
        }
    }
    float dc = dis[node];
    float2 self = __half22float2(*((const __half2*)(xws + (size_t)node * F_OUT) + f2));
    float2 bi = *((const float2*)bias + f2);
    float a = pa[0];
    float vx = (accx + self.x) * dc + bi.x;
    float vy = (accy + self.y) * dc + bi.y;
    float2 o;
    o.x = (vx >= 0.f) ? vx : a * vx;
    o.y = (vy >= 0.f) ? vy : a * vy;
    *((float2*)(out + (size_t)node * F_OUT) + f2) = o;
}

// =================== Fallback path (small ws): atomic scatter ============
__global__ void k0_specnorm(const float* __restrict__ W, const float* __restrict__ u,
                            float* __restrict__ Wsc) {
    __shared__ float v[F_IN];
    __shared__ float red[F_IN];
    __shared__ float scal;
    int t = threadIdx.x;
    float acc = 0.f;
    for (int i = 0; i < F_OUT; ++i) acc += W[i * F_IN + t] * u[i];
    v[t] = acc; red[t] = acc * acc;
    __syncthreads();
    if (t == 0) {
        float s = 0.f;
        for (int i = 0; i < F_IN; ++i) s += red[i];
        scal = 1.0f / fmaxf(sqrtf(s), 1e-12f);
    }
    __syncthreads();
    v[t] *= scal;
    __syncthreads();
    if (t < F_OUT) {
        float a2 = 0.f;
        for (int j = 0; j < F_IN; ++j) a2 += W[t * F_IN + j] * v[j];
        red[t] = a2 * a2;
    }
    __syncthreads();
    if (t == 0) {
        float s = 0.f;
        for (int i = 0; i < F_OUT; ++i) s += red[i];
        scal = 1.0f / fmaxf(sqrtf(s), 1e-30f);
    }
    __syncthreads();
    float is = scal;
    for (int i = 0; i < F_OUT; ++i)
        Wsc[i * F_IN + t] = W[i * F_IN + t] * is;
}

__global__ void k1_xw_f32(const float* __restrict__ x, const float* __restrict__ Wsc,
                          const float* __restrict__ dis, float* __restrict__ xw, int Nn) {
    int id = blockIdx.x * blockDim.x + threadIdx.x;
    if (id >= Nn * F_OUT) return;
    int r = id >> 5, f = id & 31;
    const float4* x4 = (const float4*)(x + (size_t)r * F_IN);
    const float4* w4 = (const float4*)(Wsc + (size_t)f * F_IN);
    float acc = 0.f;
#pragma unroll
    for (int k = 0; k < F_IN / 4; ++k) {
        float4 a = x4[k];
        float4 b = w4[k];
        acc += a.x * b.x + a.y * b.y + a.z * b.z + a.w * b.w;
    }
    xw[id] = acc * dis[r];
}

__global__ void k2_deg(const int* __restrict__ col, int* __restrict__ cnt, int E_) {
    int e = blockIdx.x * blockDim.x + threadIdx.x;
    if (e < E_) atomicAdd(&cnt[col[e]], 1);
}

__global__ void k3_dis(const int* __restrict__ cnt, float* __restrict__ dis, int Nn) {
    int i = blockIdx.x * blockDim.x + threadIdx.x;
    if (i < Nn) dis[i] = rsqrtf((float)cnt[i] + 1.0f);
}

__global__ void k4_scatter(const int* __restrict__ ei, const float* __restrict__ xws,
                           const float* __restrict__ dis, float* __restrict__ out, int E_) {
    int id = blockIdx.x * blockDim.x + threadIdx.x;
    if (id >= E_ * F_OUT) return;
    int e = id >> 5, f = id & 31;
    int r = ei[e];
    int c = ei[E_ + e];
    atomicAdd(&out[(size_t)c * F_OUT + f], xws[(size_t)r * F_OUT + f] * dis[c]);
}

__global__ void k5_epi(const float* __restrict__ xws, const float* __restrict__ dis,
                       const float* __restrict__ bias, const float* __restrict__ pa,
                       float* __restrict__ out, int Nn) {
    int id = blockIdx.x * blockDim.x + threadIdx.x;
    if (id >= Nn * F_OUT) return;
    int i = id >> 5, f = id & 31;
    float d = dis[i];
    float v = out[id] + xws[id] * d + bias[f];
    float a = pa[0];
    out[id] = (v >= 0.f) ? v : a * v;
}

extern "C" void kernel_launch(void* const* d_in, const int* in_sizes, int n_in,
                              void* d_out, int out_size, void* d_ws, size_t ws_size,
                              hipStream_t stream) {
    const float* x    = (const float*)d_in[0];
    const int*   ei   = (const int*)d_in[1];   // [2,E]: row = ei[0:E], col = ei[E:2E]
    const float* W    = (const float*)d_in[2];
    const float* bias = (const float*)d_in[3];
    const float* pa   = (const float*)d_in[4];
    const float* u    = (const float*)d_in[5];

    int Nn = in_sizes[0] / F_IN;   // 100000
    int E_ = in_sizes[1] / 2;      // 1600000
    float* out = (float*)d_out;

    int NB = (Nn + BMSK) >> BSH;   // 128-node buckets (782)

    // ws layout (4B words):
    // xwh [N*16] | dis [N] | cursor [N+1] | M [NB*PBLK] | total [NB] |
    // base [NB+1] | staging [E] | esr [E]
    size_t o = 0;
    __half*   xwh     = (__half*)d_ws;       o += (size_t)Nn * (F_OUT / 2);
    float*    dis     = (float*)d_ws + o;    o += Nn;
    int*      cursor  = (int*)d_ws + o;      o += Nn + 1;
    int*      M       = (int*)d_ws + o;      o += (size_t)NB * PBLK;
    int*      total   = (int*)d_ws + o;      o += NB;
    int*      base    = (int*)d_ws + o;      o += NB + 1;
    unsigned* staging = (unsigned*)d_ws + o; o += E_;
    int*      esr     = (int*)d_ws + o;      o += E_;
    bool big_ws = (ws_size >= o * sizeof(float)) && (NB <= MAXB);

    if (big_ws) {
        k_hist<<<PBLK, 256, 0, stream>>>(ei + E_, M, E_, NB);
        k_scanA<<<NB, 256, 0, stream>>>(M, total, NB);
        k_scat1<<<PBLK, 256, 0, stream>>>(ei, M, total, base, staging, E_, NB);
        k_sort2<<<NB, 256, 0, stream>>>(staging, base, esr, dis, cursor, Nn, E_, NB);
        k1_xw<<<(Nn + 127) / 128, 256, 0, stream>>>(x, W, u, dis, xwh, Nn);
        k_gather<<<(Nn + 15) / 16, 256, 0, stream>>>(esr, cursor, xwh, dis, bias, pa, out, Nn);
    } else {
        // fp32 fallback: xw | Wsc | dis | deg
        size_t o2 = 0;
        float* xw2  = (float*)d_ws;       o2 += (size_t)Nn * F_OUT;
        float* Wsc2 = (float*)d_ws + o2;  o2 += F_OUT * F_IN;
        float* dis2 = (float*)d_ws + o2;  o2 += Nn;
        int*   deg2 = (int*)d_ws + o2;    o2 += Nn;
        hipMemsetAsync(deg2, 0, (size_t)Nn * sizeof(int), stream);
        hipMemsetAsync(d_out, 0, (size_t)Nn * F_OUT * sizeof(float), stream);
        k0_specnorm<<<1, 128, 0, stream>>>(W, u, Wsc2);
        k2_deg<<<(E_ + 255) / 256, 256, 0, stream>>>(ei + E_, deg2, E_);
        k3_dis<<<(Nn + 255) / 256, 256, 0, stream>>>(deg2, dis2, Nn);
        int nT1 = Nn * F_OUT;
        k1_xw_f32<<<(nT1 + 255) / 256, 256, 0, stream>>>(x, Wsc2, dis2, xw2, Nn);
        int nT4 = E_ * F_OUT;
        k4_scatter<<<(nT4 + 255) / 256, 256, 0, stream>>>(ei, xw2, dis2, out, E_);
        k5_epi<<<(nT1 + 255) / 256, 256, 0, stream>>>(xw2, dis2, bias, pa, out, Nn);
    }
}

// Round 9
// 177.803 us; speedup vs baseline: 1.0733x; 1.0733x over previous
//
#include <hip/hip_runtime.h>
#include <hip/hip_fp16.h>

#define F_IN 128
#define F_OUT 32
#define PBLK 256   // phase-1 partition blocks (proven locality at 256)
#define BSH 8      // 256 nodes per bucket (R5-proven)
#define BMSK 255
#define MAXB 512   // max buckets (N <= 131072)

// ============ L1: k_hist — per-partition bucket histogram -> M[b][p] ======
__global__ __launch_bounds__(256) void k_hist(const int* __restrict__ col,
                                              int* __restrict__ M, int E_, int NB) {
    __shared__ int h[MAXB];
    int p = blockIdx.x, t = threadIdx.x;
    for (int b = t; b < NB; b += 256) h[b] = 0;
    __syncthreads();
    int epb = (E_ + PBLK - 1) / PBLK;
    int e0 = p * epb, e1 = min(e0 + epb, E_);
    for (int e = e0 + t; e < e1; e += 256)
        atomicAdd(&h[col[e] >> BSH], 1);            // LDS atomic
    __syncthreads();
    for (int b = t; b < NB; b += 256) M[(size_t)b * PBLK + p] = h[b];
}

// ============ L2: k_scanA — per-bucket exclusive scan over partitions =====
__global__ __launch_bounds__(256) void k_scanA(int* __restrict__ M,
                                               int* __restrict__ total, int NB) {
    __shared__ int sd[256];
    int b = blockIdx.x, t = threadIdx.x;
    int v = M[(size_t)b * PBLK + t];
    sd[t] = v;
    __syncthreads();
    for (int o = 1; o < 256; o <<= 1) {
        int u = (t >= o) ? sd[t - o] : 0;
        __syncthreads();
        sd[t] += u;
        __syncthreads();
    }
    M[(size_t)b * PBLK + t] = sd[t] - v;
    if (t == 255) total[b] = sd[255];
}

// ============ L3: k_scat1 — redundant base-scan + partition scatter =======
__global__ __launch_bounds__(256) void k_scat1(
    const int* __restrict__ ei, const int* __restrict__ M,
    const int* __restrict__ total, int* __restrict__ base,
    unsigned* __restrict__ staging, int E_, int NB) {
    __shared__ int scur[MAXB];
    __shared__ int sd[256];
    int p = blockIdx.x, t = threadIdx.x;
    // redundant exclusive scan of total[0..NB) (NB <= 512 -> C <= 2)
    int C = (NB + 255) >> 8;
    int vals[2];
    int run = 0;
    for (int j = 0; j < C; ++j) {
        int b = t * C + j;
        int v = (b < NB) ? total[b] : 0;
        vals[j] = run;
        run += v;
    }
    int tsum = run;
    sd[t] = tsum;
    __syncthreads();
    for (int o = 1; o < 256; o <<= 1) {
        int u = (t >= o) ? sd[t - o] : 0;
        __syncthreads();
        sd[t] += u;
        __syncthreads();
    }
    int cb = sd[t] - tsum;
    for (int j = 0; j < C; ++j) {
        int b = t * C + j;
        if (b < NB) {
            int sb = cb + vals[j];
            scur[b] = sb + M[(size_t)b * PBLK + p];
            if (p == 0) base[b] = sb;
        }
    }
    if (p == 0 && t == 255) base[NB] = sd[255];  // == E
    __syncthreads();
    int epb = (E_ + PBLK - 1) / PBLK;
    int e0 = p * epb, e1 = min(e0 + epb, E_);
    const int* col = ei + E_;
    for (int e = e0 + t; e < e1; e += 256) {
        int c = col[e];
        int r = ei[e];
        int pos = atomicAdd(&scur[c >> BSH], 1);   // LDS atomic (block-private)
        staging[pos] = ((unsigned)r << BSH) | (unsigned)(c & BMSK);
    }
}

// ============ L4: k_sort2 — per-bucket sort + deg/dis/cursor ==============
__global__ __launch_bounds__(256) void k_sort2(
    const unsigned* __restrict__ staging, const int* __restrict__ base,
    int* __restrict__ esr, float* __restrict__ dis,
    int* __restrict__ cursor, int Nn, int E_, int NB) {
    __shared__ int hist[256];
    __shared__ int sd[256];
    __shared__ int lcur[256];
    int b = blockIdx.x, t = threadIdx.x;
    int nb0 = b << BSH;
    int nc = min(1 << BSH, Nn - nb0);
    hist[t] = 0;
    __syncthreads();
    int s0 = base[b], s1 = base[b + 1];
    for (int j = s0 + t; j < s1; j += 256)
        atomicAdd(&hist[staging[j] & BMSK], 1);    // LDS atomic
    __syncthreads();
    int h = hist[t];
    if (t < nc) dis[nb0 + t] = rsqrtf((float)h + 1.0f);
    sd[t] = h;
    __syncthreads();
    for (int o = 1; o < 256; o <<= 1) {
        int u = (t >= o) ? sd[t - o] : 0;
        __syncthreads();
        sd[t] += u;
        __syncthreads();
    }
    int excl = sd[t] - h;
    if (t < nc) cursor[nb0 + t] = s0 + excl;
    if (b == NB - 1 && t == 0) cursor[Nn] = E_;
    lcur[t] = s0 + excl;
    __syncthreads();
    for (int j = s0 + t; j < s1; j += 256) {
        unsigned v = staging[j];
        int pp = atomicAdd(&lcur[v & BMSK], 1);    // LDS atomic
        esr[pp] = (int)(v >> BSH);
    }
}

// ============ L5: k1_xw — fused specnorm + matmul, xwh = f16(xW^T * dis) ==
__global__ __launch_bounds__(256) void k1_xw(
    const float* __restrict__ x, const float* __restrict__ W,
    const float* __restrict__ u, const float* __restrict__ dis,
    __half* __restrict__ xwh, int Nn) {
    __shared__ float xs[128 * 65];
    __shared__ float wt[128 * 32];
    __shared__ float sv[F_IN];
    __shared__ float sr[F_IN];
    __shared__ float ssc;
    int t = threadIdx.x;

    // ---- redundant spectral norm (per block; W is 16 KB, L2-hot) ----
    if (t < F_IN) {
        float a = 0.f;
        for (int i = 0; i < F_OUT; ++i) a += W[i * F_IN + t] * u[i];
        sv[t] = a; sr[t] = a * a;
    }
    __syncthreads();
    for (int o = 64; o > 0; o >>= 1) {
        if (t < o) sr[t] += sr[t + o];
        __syncthreads();
    }
    if (t == 0) ssc = 1.0f / fmaxf(sqrtf(sr[0]), 1e-12f);
    __syncthreads();
    if (t < F_IN) sv[t] *= ssc;
    __syncthreads();
    if (t < F_OUT) {
        float a = 0.f;
        for (int j = 0; j < F_IN; ++j) a += W[t * F_IN + j] * sv[j];
        sr[t] = a * a;
    }
    __syncthreads();
    for (int o = 16; o > 0; o >>= 1) {
        if (t < o) sr[t] += sr[t + o];
        __syncthreads();
    }
    if (t == 0) ssc = 1.0f / fmaxf(sqrtf(sr[0]), 1e-30f);  // 1/sigma
    __syncthreads();
    float is = ssc;

    // ---- matmul tile ----
    int rbase = blockIdx.x * 128;
    {   // stage W transposed, scaled by 1/sigma
        int f = t >> 3;
        int kb = 16 * (t & 7);
        const float4* wrow = (const float4*)(W + (size_t)f * F_IN + kb);
#pragma unroll
        for (int j = 0; j < 4; ++j) {
            float4 w = wrow[j];
            int k = kb + 4 * j;
            wt[(k + 0) * 32 + f] = w.x * is;
            wt[(k + 1) * 32 + f] = w.y * is;
            wt[(k + 2) * 32 + f] = w.z * is;
            wt[(k + 3) * 32 + f] = w.w * is;
        }
    }

    int r0 = (t >> 3) * 4;
    int f0 = (t & 7) * 4;
    float4 acc0 = {0, 0, 0, 0}, acc1 = {0, 0, 0, 0};
    float4 acc2 = {0, 0, 0, 0}, acc3 = {0, 0, 0, 0};
    const float4* wt4 = (const float4*)wt;
    int fq = f0 >> 2;

    for (int kc = 0; kc < 2; ++kc) {
        __syncthreads();
        {
            int rr = t >> 4;
            int k0 = 4 * (t & 15);
#pragma unroll
            for (int pi = 0; pi < 8; ++pi) {
                int r = pi * 16 + rr;
                int grow = rbase + r;
                if (grow >= Nn) grow = Nn - 1;
                float4 v = *(const float4*)(x + (size_t)grow * F_IN + kc * 64 + k0);
                xs[r * 65 + k0 + 0] = v.x;
                xs[r * 65 + k0 + 1] = v.y;
                xs[r * 65 + k0 + 2] = v.z;
                xs[r * 65 + k0 + 3] = v.w;
            }
        }
        __syncthreads();
#pragma unroll 4
        for (int kk = 0; kk < 64; ++kk) {
            int k = kc * 64 + kk;
            float4 w = wt4[k * 8 + fq];
            float x0 = xs[(r0 + 0) * 65 + kk];
            float x1 = xs[(r0 + 1) * 65 + kk];
            float x2 = xs[(r0 + 2) * 65 + kk];
            float x3 = xs[(r0 + 3) * 65 + kk];
            acc0.x += x0 * w.x; acc0.y += x0 * w.y; acc0.z += x0 * w.z; acc0.w += x0 * w.w;
            acc1.x += x1 * w.x; acc1.y += x1 * w.y; acc1.z += x1 * w.z; acc1.w += x1 * w.w;
            acc2.x += x2 * w.x; acc2.y += x2 * w.y; acc2.z += x2 * w.z; acc2.w += x2 * w.w;
            acc3.x += x3 * w.x; acc3.y += x3 * w.y; acc3.z += x3 * w.z; acc3.w += x3 * w.w;
        }
    }
    int g0 = rbase + r0;
#pragma unroll
    for (int q = 0; q < 4; ++q) {
        int g = g0 + q;
        if (g < Nn) {
            float d = dis[g];
            float4 a = (q == 0) ? acc0 : (q == 1) ? acc1 : (q == 2) ? acc2 : acc3;
            ushort4 s;
            s.x = __half_as_ushort(__float2half(a.x * d));
            s.y = __half_as_ushort(__float2half(a.y * d));
            s.z = __half_as_ushort(__float2half(a.z * d));
            s.w = __half_as_ushort(__float2half(a.w * d));
            *(ushort4*)(xwh + (size_t)g * F_OUT + f0) = s;
        }
    }
}

// ============ L6: k_gather — 8-lane groups, ushort4 (8B) loads, unroll 8 ==
// 32 nodes per 256-thread block; a wave holds 8 groups x 8-deep MLP = 64
// concurrent row loads (vs 16 in the 16-lane/unroll-4 variant).
__device__ __forceinline__ void acc_row(const __half* xws, int r, int f4, float4& acc) {
    uint2 raw = *((const uint2*)(xws + (size_t)r * F_OUT) + f4);
    __half2 h0 = *reinterpret_cast<__half2*>(&raw.x);
    __half2 h1 = *reinterpret_cast<__half2*>(&raw.y);
    float2 fa = __half22float2(h0);
    float2 fb = __half22float2(h1);
    acc.x += fa.x; acc.y += fa.y; acc.z += fb.x; acc.w += fb.y;
}

__global__ __launch_bounds__(256) void k_gather(
    const int* __restrict__ esr, const int* __restrict__ cursor,
    const __half* __restrict__ xws, const float* __restrict__ dis,
    const float* __restrict__ bias, const float* __restrict__ pa,
    float* __restrict__ out, int Nn) {
    int t = threadIdx.x;
    int node = blockIdx.x * 32 + (t >> 3);
    if (node >= Nn) return;
    int f4 = t & 7;  // features 4*f4 .. 4*f4+3
    int start = cursor[node], end = cursor[node + 1];
    float4 acc = {0, 0, 0, 0};
    int j0 = start;
    for (; j0 + 8 <= end; j0 += 8) {
        int rf = esr[j0 + f4];
        int r0 = __shfl(rf, 0, 8), r1 = __shfl(rf, 1, 8);
        int r2 = __shfl(rf, 2, 8), r3 = __shfl(rf, 3, 8);
        int r4 = __shfl(rf, 4, 8), r5 = __shfl(rf, 5, 8);
        int r6 = __shfl(rf, 6, 8), r7 = __shfl(rf, 7, 8);
        acc_row(xws, r0, f4, acc); acc_row(xws, r1, f4, acc);
        acc_row(xws, r2, f4, acc); acc_row(xws, r3, f4, acc);
        acc_row(xws, r4, f4, acc); acc_row(xws, r5, f4, acc);
        acc_row(xws, r6, f4, acc); acc_row(xws, r7, f4, acc);
    }
    if (j0 < end) {
        int idx = j0 + f4;
        int rf = (idx < end) ? esr[idx] : 0;
        int m = end - j0;
        for (int i = 0; i < m; ++i) {
            int r = __shfl(rf, i, 8);
            acc_row(xws, r, f4, acc);
        }
    }
    float dc = dis[node];
    float4 self;
    {
        uint2 raw = *((const uint2*)(xws + (size_t)node * F_OUT) + f4);
        __half2 h0 = *reinterpret_cast<__half2*>(&raw.x);
        __half2 h1 = *reinterpret_cast<__half2*>(&raw.y);
        float2 fa = __half22float2(h0);
        float2 fb = __half22float2(h1);
        self = make_float4(fa.x, fa.y, fb.x, fb.y);
    }
    float4 bi = *((const float4*)bias + f4);
    float a = pa[0];
    float4 o;
    o.x = (acc.x + self.x) * dc + bi.x;
    o.y = (acc.y + self.y) * dc + bi.y;
    o.z = (acc.z + self.z) * dc + bi.z;
    o.w = (acc.w + self.w) * dc + bi.w;
    o.x = (o.x >= 0.f) ? o.x : a * o.x;
    o.y = (o.y >= 0.f) ? o.y : a * o.y;
    o.z = (o.z >= 0.f) ? o.z : a * o.z;
    o.w = (o.w >= 0.f) ? o.w : a * o.w;
    *((float4*)(out + (size_t)node * F_OUT) + f4) = o;
}

// =================== Fallback path (small ws): atomic scatter ============
__global__ void k0_specnorm(const float* __restrict__ W, const float* __restrict__ u,
                            float* __restrict__ Wsc) {
    __shared__ float v[F_IN];
    __shared__ float red[F_IN];
    __shared__ float scal;
    int t = threadIdx.x;
    float acc = 0.f;
    for (int i = 0; i < F_OUT; ++i) acc += W[i * F_IN + t] * u[i];
    v[t] = acc; red[t] = acc * acc;
    __syncthreads();
    if (t == 0) {
        float s = 0.f;
        for (int i = 0; i < F_IN; ++i) s += red[i];
        scal = 1.0f / fmaxf(sqrtf(s), 1e-12f);
    }
    __syncthreads();
    v[t] *= scal;
    __syncthreads();
    if (t < F_OUT) {
        float a2 = 0.f;
        for (int j = 0; j < F_IN; ++j) a2 += W[t * F_IN + j] * v[j];
        red[t] = a2 * a2;
    }
    __syncthreads();
    if (t == 0) {
        float s = 0.f;
        for (int i = 0; i < F_OUT; ++i) s += red[i];
        scal = 1.0f / fmaxf(sqrtf(s), 1e-30f);
    }
    __syncthreads();
    float is = scal;
    for (int i = 0; i < F_OUT; ++i)
        Wsc[i * F_IN + t] = W[i * F_IN + t] * is;
}

__global__ void k1_xw_f32(const float* __restrict__ x, const float* __restrict__ Wsc,
                          const float* __restrict__ dis, float* __restrict__ xw, int Nn) {
    int id = blockIdx.x * blockDim.x + threadIdx.x;
    if (id >= Nn * F_OUT) return;
    int r = id >> 5, f = id & 31;
    const float4* x4 = (const float4*)(x + (size_t)r * F_IN);
    const float4* w4 = (const float4*)(Wsc + (size_t)f * F_IN);
    float acc = 0.f;
#pragma unroll
    for (int k = 0; k < F_IN / 4; ++k) {
        float4 a = x4[k];
        float4 b = w4[k];
        acc += a.x * b.x + a.y * b.y + a.z * b.z + a.w * b.w;
    }
    xw[id] = acc * dis[r];
}

__global__ void k2_deg(const int* __restrict__ col, int* __restrict__ cnt, int E_) {
    int e = blockIdx.x * blockDim.x + threadIdx.x;
    if (e < E_) atomicAdd(&cnt[col[e]], 1);
}

__global__ void k3_dis(const int* __restrict__ cnt, float* __restrict__ dis, int Nn) {
    int i = blockIdx.x * blockDim.x + threadIdx.x;
    if (i < Nn) dis[i] = rsqrtf((float)cnt[i] + 1.0f);
}

__global__ void k4_scatter(const int* __restrict__ ei, const float* __restrict__ xws,
                           const float* __restrict__ dis, float* __restrict__ out, int E_) {
    int id = blockIdx.x * blockDim.x + threadIdx.x;
    if (id >= E_ * F_OUT) return;
    int e = id >> 5, f = id & 31;
    int r = ei[e];
    int c = ei[E_ + e];
    atomicAdd(&out[(size_t)c * F_OUT + f], xws[(size_t)r * F_OUT + f] * dis[c]);
}

__global__ void k5_epi(const float* __restrict__ xws, const float* __restrict__ dis,
                       const float* __restrict__ bias, const float* __restrict__ pa,
                       float* __restrict__ out, int Nn) {
    int id = blockIdx.x * blockDim.x + threadIdx.x;
    if (id >= Nn * F_OUT) return;
    int i = id >> 5, f = id & 31;
    float d = dis[i];
    float v = out[id] + xws[id] * d + bias[f];
    float a = pa[0];
    out[id] = (v >= 0.f) ? v : a * v;
}

extern "C" void kernel_launch(void* const* d_in, const int* in_sizes, int n_in,
                              void* d_out, int out_size, void* d_ws, size_t ws_size,
                              hipStream_t stream) {
    const float* x    = (const float*)d_in[0];
    const int*   ei   = (const int*)d_in[1];   // [2,E]: row = ei[0:E], col = ei[E:2E]
    const float* W    = (const float*)d_in[2];
    const float* bias = (const float*)d_in[3];
    const float* pa   = (const float*)d_in[4];
    const float* u    = (const float*)d_in[5];

    int Nn = in_sizes[0] / F_IN;   // 100000
    int E_ = in_sizes[1] / 2;      // 1600000
    float* out = (float*)d_out;

    int NB = (Nn + BMSK) >> BSH;   // 256-node buckets (391)

    // ws layout (4B words):
    // xwh [N*16] | dis [N] | cursor [N+1] | M [NB*PBLK] | total [NB] |
    // base [NB+1] | staging [E] | esr [E]
    size_t o = 0;
    __half*   xwh     = (__half*)d_ws;       o += (size_t)Nn * (F_OUT / 2);
    float*    dis     = (float*)d_ws + o;    o += Nn;
    int*      cursor  = (int*)d_ws + o;      o += Nn + 1;
    int*      M       = (int*)d_ws + o;      o += (size_t)NB * PBLK;
    int*      total   = (int*)d_ws + o;      o += NB;
    int*      base    = (int*)d_ws + o;      o += NB + 1;
    unsigned* staging = (unsigned*)d_ws + o; o += E_;
    int*      esr     = (int*)d_ws + o;      o += E_;
    bool big_ws = (ws_size >= o * sizeof(float)) && (NB <= MAXB);

    if (big_ws) {
        k_hist<<<PBLK, 256, 0, stream>>>(ei + E_, M, E_, NB);
        k_scanA<<<NB, 256, 0, stream>>>(M, total, NB);
        k_scat1<<<PBLK, 256, 0, stream>>>(ei, M, total, base, staging, E_, NB);
        k_sort2<<<NB, 256, 0, stream>>>(staging, base, esr, dis, cursor, Nn, E_, NB);
        k1_xw<<<(Nn + 127) / 128, 256, 0, stream>>>(x, W, u, dis, xwh, Nn);
        k_gather<<<(Nn + 31) / 32, 256, 0, stream>>>(esr, cursor, xwh, dis, bias, pa, out, Nn);
    } else {
        // fp32 fallback: xw | Wsc | dis | deg
        size_t o2 = 0;
        float* xw2  = (float*)d_ws;       o2 += (size_t)Nn * F_OUT;
        float* Wsc2 = (float*)d_ws + o2;  o2 += F_OUT * F_IN;
        float* dis2 = (float*)d_ws + o2;  o2 += Nn;
        int*   deg2 = (int*)d_ws + o2;    o2 += Nn;
        hipMemsetAsync(deg2, 0, (size_t)Nn * sizeof(int), stream);
        hipMemsetAsync(d_out, 0, (size_t)Nn * F_OUT * sizeof(float), stream);
        k0_specnorm<<<1, 128, 0, stream>>>(W, u, Wsc2);
        k2_deg<<<(E_ + 255) / 256, 256, 0, stream>>>(ei + E_, deg2, E_);
        k3_dis<<<(Nn + 255) / 256, 256, 0, stream>>>(deg2, dis2, Nn);
        int nT1 = Nn * F_OUT;
        k1_xw_f32<<<(nT1 + 255) / 256, 256, 0, stream>>>(x, Wsc2, dis2, xw2, Nn);
        int nT4 = E_ * F_OUT;
        k4_scatter<<<(nT4 + 255) / 256, 256, 0, stream>>>(ei, xw2, dis2, out, E_);
        k5_epi<<<(nT1 + 255) / 256, 256, 0, stream>>>(xw2, dis2, bias, pa, out, Nn);
    }
}

// Round 10
// 176.483 us; speedup vs baseline: 1.0813x; 1.0075x over previous
//
#include <hip/hip_runtime.h>
#include <hip/hip_fp16.h>

#define F_IN 128
#define F_OUT 32
#define PBLK 512   // phase-1 partition blocks (2/CU: shorter serial span)
#define BSH 8      // 256 nodes per bucket (R5/R9-proven)
#define BMSK 255
#define MAXB 512   // max buckets (N <= 131072)

// ============ L1: k_hist — per-partition bucket histogram -> M[b][p] ======
__global__ __launch_bounds__(256) void k_hist(const int* __restrict__ col,
                                              int* __restrict__ M, int E_, int NB) {
    __shared__ int h[MAXB];
    int p = blockIdx.x, t = threadIdx.x;
    for (int b = t; b < NB; b += 256) h[b] = 0;
    __syncthreads();
    int epb = (E_ + PBLK - 1) / PBLK;
    int e0 = p * epb, e1 = min(e0 + epb, E_);
    for (int e = e0 + t; e < e1; e += 256)
        atomicAdd(&h[col[e] >> BSH], 1);            // LDS atomic
    __syncthreads();
    for (int b = t; b < NB; b += 256) M[(size_t)b * PBLK + p] = h[b];
}

// ============ L2: k_scanA — per-bucket exclusive scan over P=512 parts ====
__global__ __launch_bounds__(256) void k_scanA(int* __restrict__ M,
                                               int* __restrict__ total, int NB) {
    __shared__ int sd[256];
    int b = blockIdx.x, t = threadIdx.x;
    int v0 = M[(size_t)b * PBLK + 2 * t];
    int v1 = M[(size_t)b * PBLK + 2 * t + 1];
    int s = v0 + v1;
    sd[t] = s;
    __syncthreads();
    for (int o = 1; o < 256; o <<= 1) {
        int u = (t >= o) ? sd[t - o] : 0;
        __syncthreads();
        sd[t] += u;
        __syncthreads();
    }
    int cb = sd[t] - s;
    M[(size_t)b * PBLK + 2 * t]     = cb;
    M[(size_t)b * PBLK + 2 * t + 1] = cb + v0;
    if (t == 255) total[b] = sd[255];
}

// ============ L3: k_scat1 — redundant base-scan + partition scatter =======
__global__ __launch_bounds__(256) void k_scat1(
    const int* __restrict__ ei, const int* __restrict__ M,
    const int* __restrict__ total, int* __restrict__ base,
    unsigned* __restrict__ staging, int E_, int NB) {
    __shared__ int scur[MAXB];
    __shared__ int sd[256];
    int p = blockIdx.x, t = threadIdx.x;
    // redundant exclusive scan of total[0..NB) (NB <= 512 -> C <= 2)
    int C = (NB + 255) >> 8;
    int vals[2];
    int run = 0;
    for (int j = 0; j < C; ++j) {
        int b = t * C + j;
        int v = (b < NB) ? total[b] : 0;
        vals[j] = run;
        run += v;
    }
    int tsum = run;
    sd[t] = tsum;
    __syncthreads();
    for (int o = 1; o < 256; o <<= 1) {
        int u = (t >= o) ? sd[t - o] : 0;
        __syncthreads();
        sd[t] += u;
        __syncthreads();
    }
    int cb = sd[t] - tsum;
    for (int j = 0; j < C; ++j) {
        int b = t * C + j;
        if (b < NB) {
            int sb = cb + vals[j];
            scur[b] = sb + M[(size_t)b * PBLK + p];
            if (p == 0) base[b] = sb;
        }
    }
    if (p == 0 && t == 255) base[NB] = sd[255];  // == E
    __syncthreads();
    int epb = (E_ + PBLK - 1) / PBLK;
    int e0 = p * epb, e1 = min(e0 + epb, E_);
    const int* col = ei + E_;
    for (int e = e0 + t; e < e1; e += 256) {
        int c = col[e];
        int r = ei[e];
        int pos = atomicAdd(&scur[c >> BSH], 1);   // LDS atomic (block-private)
        staging[pos] = ((unsigned)r << BSH) | (unsigned)(c & BMSK);
    }
}

// ============ L4: k_sort2 — per-bucket sort + deg/dis/cursor (512 thr) ====
__global__ __launch_bounds__(512) void k_sort2(
    const unsigned* __restrict__ staging, const int* __restrict__ base,
    int* __restrict__ esr, float* __restrict__ dis,
    int* __restrict__ cursor, int Nn, int E_, int NB) {
    __shared__ int hist[256];
    __shared__ int sd[256];
    __shared__ int lcur[256];
    int b = blockIdx.x, t = threadIdx.x;
    int nb0 = b << BSH;
    int nc = min(1 << BSH, Nn - nb0);
    if (t < 256) hist[t] = 0;
    __syncthreads();
    int s0 = base[b], s1 = base[b + 1];
    for (int j = s0 + t; j < s1; j += 512)
        atomicAdd(&hist[staging[j] & BMSK], 1);    // LDS atomic
    __syncthreads();
    int h = 0;
    if (t < 256) {
        h = hist[t];
        if (t < nc) dis[nb0 + t] = rsqrtf((float)h + 1.0f);
        sd[t] = h;
    }
    __syncthreads();
    for (int o = 1; o < 256; o <<= 1) {
        int u = 0;
        if (t < 256 && t >= o) u = sd[t - o];
        __syncthreads();
        if (t < 256) sd[t] += u;
        __syncthreads();
    }
    if (t < 256) {
        int excl = sd[t] - h;
        if (t < nc) cursor[nb0 + t] = s0 + excl;
        lcur[t] = s0 + excl;
    }
    if (b == NB - 1 && t == 0) cursor[Nn] = E_;
    __syncthreads();
    for (int j = s0 + t; j < s1; j += 512) {
        unsigned v = staging[j];
        int pp = atomicAdd(&lcur[v & BMSK], 1);    // LDS atomic
        esr[pp] = (int)(v >> BSH);
    }
}

// ============ L5: k1_xw — fused specnorm + matmul, xwh = f16(xW^T * dis) ==
__global__ __launch_bounds__(256) void k1_xw(
    const float* __restrict__ x, const float* __restrict__ W,
    const float* __restrict__ u, const float* __restrict__ dis,
    __half* __restrict__ xwh, int Nn) {
    __shared__ float xs[128 * 65];
    __shared__ float wt[128 * 32];
    __shared__ float sv[F_IN];
    __shared__ float sr[F_IN];
    __shared__ float ssc;
    int t = threadIdx.x;

    // ---- redundant spectral norm (per block; W is 16 KB, L2-hot) ----
    if (t < F_IN) {
        float a = 0.f;
        for (int i = 0; i < F_OUT; ++i) a += W[i * F_IN + t] * u[i];
        sv[t] = a; sr[t] = a * a;
    }
    __syncthreads();
    for (int o = 64; o > 0; o >>= 1) {
        if (t < o) sr[t] += sr[t + o];
        __syncthreads();
    }
    if (t == 0) ssc = 1.0f / fmaxf(sqrtf(sr[0]), 1e-12f);
    __syncthreads();
    if (t < F_IN) sv[t] *= ssc;
    __syncthreads();
    if (t < F_OUT) {
        float a = 0.f;
        for (int j = 0; j < F_IN; ++j) a += W[t * F_IN + j] * sv[j];
        sr[t] = a * a;
    }
    __syncthreads();
    for (int o = 16; o > 0; o >>= 1) {
        if (t < o) sr[t] += sr[t + o];
        __syncthreads();
    }
    if (t == 0) ssc = 1.0f / fmaxf(sqrtf(sr[0]), 1e-30f);  // 1/sigma
    __syncthreads();
    float is = ssc;

    // ---- matmul tile ----
    int rbase = blockIdx.x * 128;
    {   // stage W transposed, scaled by 1/sigma
        int f = t >> 3;
        int kb = 16 * (t & 7);
        const float4* wrow = (const float4*)(W + (size_t)f * F_IN + kb);
#pragma unroll
        for (int j = 0; j < 4; ++j) {
            float4 w = wrow[j];
            int k = kb + 4 * j;
            wt[(k + 0) * 32 + f] = w.x * is;
            wt[(k + 1) * 32 + f] = w.y * is;
            wt[(k + 2) * 32 + f] = w.z * is;
            wt[(k + 3) * 32 + f] = w.w * is;
        }
    }

    int r0 = (t >> 3) * 4;
    int f0 = (t & 7) * 4;
    float4 acc0 = {0, 0, 0, 0}, acc1 = {0, 0, 0, 0};
    float4 acc2 = {0, 0, 0, 0}, acc3 = {0, 0, 0, 0};
    const float4* wt4 = (const float4*)wt;
    int fq = f0 >> 2;

    for (int kc = 0; kc < 2; ++kc) {
        __syncthreads();
        {
            int rr = t >> 4;
            int k0 = 4 * (t & 15);
#pragma unroll
            for (int pi = 0; pi < 8; ++pi) {
                int r = pi * 16 + rr;
                int grow = rbase + r;
                if (grow >= Nn) grow = Nn - 1;
                float4 v = *(const float4*)(x + (size_t)grow * F_IN + kc * 64 + k0);
                xs[r * 65 + k0 + 0] = v.x;
                xs[r * 65 + k0 + 1] = v.y;
                xs[r * 65 + k0 + 2] = v.z;
                xs[r * 65 + k0 + 3] = v.w;
            }
        }
        __syncthreads();
#pragma unroll 4
        for (int kk = 0; kk < 64; ++kk) {
            int k = kc * 64 + kk;
            float4 w = wt4[k * 8 + fq];
            float x0 = xs[(r0 + 0) * 65 + kk];
            float x1 = xs[(r0 + 1) * 65 + kk];
            float x2 = xs[(r0 + 2) * 65 + kk];
            float x3 = xs[(r0 + 3) * 65 + kk];
            acc0.x += x0 * w.x; acc0.y += x0 * w.y; acc0.z += x0 * w.z; acc0.w += x0 * w.w;
            acc1.x += x1 * w.x; acc1.y += x1 * w.y; acc1.z += x1 * w.z; acc1.w += x1 * w.w;
            acc2.x += x2 * w.x; acc2.y += x2 * w.y; acc2.z += x2 * w.z; acc2.w += x2 * w.w;
            acc3.x += x3 * w.x; acc3.y += x3 * w.y; acc3.z += x3 * w.z; acc3.w += x3 * w.w;
        }
    }
    int g0 = rbase + r0;
#pragma unroll
    for (int q = 0; q < 4; ++q) {
        int g = g0 + q;
        if (g < Nn) {
            float d = dis[g];
            float4 a = (q == 0) ? acc0 : (q == 1) ? acc1 : (q == 2) ? acc2 : acc3;
            ushort4 s;
            s.x = __half_as_ushort(__float2half(a.x * d));
            s.y = __half_as_ushort(__float2half(a.y * d));
            s.z = __half_as_ushort(__float2half(a.z * d));
            s.w = __half_as_ushort(__float2half(a.w * d));
            *(ushort4*)(xwh + (size_t)g * F_OUT + f0) = s;
        }
    }
}

// ============ L6: k_gather — 8-lane groups, ushort4 loads, 512 threads ====
__device__ __forceinline__ void acc_row(const __half* xws, int r, int f4, float4& acc) {
    uint2 raw = *((const uint2*)(xws + (size_t)r * F_OUT) + f4);
    __half2 h0 = *reinterpret_cast<__half2*>(&raw.x);
    __half2 h1 = *reinterpret_cast<__half2*>(&raw.y);
    float2 fa = __half22float2(h0);
    float2 fb = __half22float2(h1);
    acc.x += fa.x; acc.y += fa.y; acc.z += fb.x; acc.w += fb.y;
}

__global__ __launch_bounds__(512) void k_gather(
    const int* __restrict__ esr, const int* __restrict__ cursor,
    const __half* __restrict__ xws, const float* __restrict__ dis,
    const float* __restrict__ bias, const float* __restrict__ pa,
    float* __restrict__ out, int Nn) {
    int t = threadIdx.x;
    int node = blockIdx.x * 64 + (t >> 3);
    if (node >= Nn) return;
    int f4 = t & 7;  // features 4*f4 .. 4*f4+3
    int start = cursor[node], end = cursor[node + 1];
    float4 acc = {0, 0, 0, 0};
    int j0 = start;
    for (; j0 + 8 <= end; j0 += 8) {
        int rf = esr[j0 + f4];
        int r0 = __shfl(rf, 0, 8), r1 = __shfl(rf, 1, 8);
        int r2 = __shfl(rf, 2, 8), r3 = __shfl(rf, 3, 8);
        int r4 = __shfl(rf, 4, 8), r5 = __shfl(rf, 5, 8);
        int r6 = __shfl(rf, 6, 8), r7 = __shfl(rf, 7, 8);
        acc_row(xws, r0, f4, acc); acc_row(xws, r1, f4, acc);
        acc_row(xws, r2, f4, acc); acc_row(xws, r3, f4, acc);
        acc_row(xws, r4, f4, acc); acc_row(xws, r5, f4, acc);
        acc_row(xws, r6, f4, acc); acc_row(xws, r7, f4, acc);
    }
    if (j0 < end) {
        int idx = j0 + f4;
        int rf = (idx < end) ? esr[idx] : 0;
        int m = end - j0;
        for (int i = 0; i < m; ++i) {
            int r = __shfl(rf, i, 8);
            acc_row(xws, r, f4, acc);
        }
    }
    float dc = dis[node];
    float4 self;
    {
        uint2 raw = *((const uint2*)(xws + (size_t)node * F_OUT) + f4);
        __half2 h0 = *reinterpret_cast<__half2*>(&raw.x);
        __half2 h1 = *reinterpret_cast<__half2*>(&raw.y);
        float2 fa = __half22float2(h0);
        float2 fb = __half22float2(h1);
        self = make_float4(fa.x, fa.y, fb.x, fb.y);
    }
    float4 bi = *((const float4*)bias + f4);
    float a = pa[0];
    float4 o;
    o.x = (acc.x + self.x) * dc + bi.x;
    o.y = (acc.y + self.y) * dc + bi.y;
    o.z = (acc.z + self.z) * dc + bi.z;
    o.w = (acc.w + self.w) * dc + bi.w;
    o.x = (o.x >= 0.f) ? o.x : a * o.x;
    o.y = (o.y >= 0.f) ? o.y : a * o.y;
    o.z = (o.z >= 0.f) ? o.z : a * o.z;
    o.w = (o.w >= 0.f) ? o.w : a * o.w;
    *((float4*)(out + (size_t)node * F_OUT) + f4) = o;
}

// =================== Fallback path (small ws): atomic scatter ============
__global__ void k0_specnorm(const float* __restrict__ W, const float* __restrict__ u,
                            float* __restrict__ Wsc) {
    __shared__ float v[F_IN];
    __shared__ float red[F_IN];
    __shared__ float scal;
    int t = threadIdx.x;
    float acc = 0.f;
    for (int i = 0; i < F_OUT; ++i) acc += W[i * F_IN + t] * u[i];
    v[t] = acc; red[t] = acc * acc;
    __syncthreads();
    if (t == 0) {
        float s = 0.f;
        for (int i = 0; i < F_IN; ++i) s += red[i];
        scal = 1.0f / fmaxf(sqrtf(s), 1e-12f);
    }
    __syncthreads();
    v[t] *= scal;
    __syncthreads();
    if (t < F_OUT) {
        float a2 = 0.f;
        for (int j = 0; j < F_IN; ++j) a2 += W[t * F_IN + j] * v[j];
        red[t] = a2 * a2;
    }
    __syncthreads();
    if (t == 0) {
        float s = 0.f;
        for (int i = 0; i < F_OUT; ++i) s += red[i];
        scal = 1.0f / fmaxf(sqrtf(s), 1e-30f);
    }
    __syncthreads();
    float is = scal;
    for (int i = 0; i < F_OUT; ++i)
        Wsc[i * F_IN + t] = W[i * F_IN + t] * is;
}

__global__ void k1_xw_f32(const float* __restrict__ x, const float* __restrict__ Wsc,
                          const float* __restrict__ dis, float* __restrict__ xw, int Nn) {
    int id = blockIdx.x * blockDim.x + threadIdx.x;
    if (id >= Nn * F_OUT) return;
    int r = id >> 5, f = id & 31;
    const float4* x4 = (const float4*)(x + (size_t)r * F_IN);
    const float4* w4 = (const float4*)(Wsc + (size_t)f * F_IN);
    float acc = 0.f;
#pragma unroll
    for (int k = 0; k < F_IN / 4; ++k) {
        float4 a = x4[k];
        float4 b = w4[k];
        acc += a.x * b.x + a.y * b.y + a.z * b.z + a.w * b.w;
    }
    xw[id] = acc * dis[r];
}

__global__ void k2_deg(const int* __restrict__ col, int* __restrict__ cnt, int E_) {
    int e = blockIdx.x * blockDim.x + threadIdx.x;
    if (e < E_) atomicAdd(&cnt[col[e]], 1);
}

__global__ void k3_dis(const int* __restrict__ cnt, float* __restrict__ dis, int Nn) {
    int i = blockIdx.x * blockDim.x + threadIdx.x;
    if (i < Nn) dis[i] = rsqrtf((float)cnt[i] + 1.0f);
}

__global__ void k4_scatter(const int* __restrict__ ei, const float* __restrict__ xws,
                           const float* __restrict__ dis, float* __restrict__ out, int E_) {
    int id = blockIdx.x * blockDim.x + threadIdx.x;
    if (id >= E_ * F_OUT) return;
    int e = id >> 5, f = id & 31;
    int r = ei[e];
    int c = ei[E_ + e];
    atomicAdd(&out[(size_t)c * F_OUT + f], xws[(size_t)r * F_OUT + f] * dis[c]);
}

__global__ void k5_epi(const float* __restrict__ xws, const float* __restrict__ dis,
                       const float* __restrict__ bias, const float* __restrict__ pa,
                       float* __restrict__ out, int Nn) {
    int id = blockIdx.x * blockDim.x + threadIdx.x;
    if (id >= Nn * F_OUT) return;
    int i = id >> 5, f = id & 31;
    float d = dis[i];
    float v = out[id] + xws[id] * d + bias[f];
    float a = pa[0];
    out[id] = (v >= 0.f) ? v : a * v;
}

extern "C" void kernel_launch(void* const* d_in, const int* in_sizes, int n_in,
                              void* d_out, int out_size, void* d_ws, size_t ws_size,
                              hipStream_t stream) {
    const float* x    = (const float*)d_in[0];
    const int*   ei   = (const int*)d_in[1];   // [2,E]: row = ei[0:E], col = ei[E:2E]
    const float* W    = (const float*)d_in[2];
    const float* bias = (const float*)d_in[3];
    const float* pa   = (const float*)d_in[4];
    const float* u    = (const float*)d_in[5];

    int Nn = in_sizes[0] / F_IN;   // 100000
    int E_ = in_sizes[1] / 2;      // 1600000
    float* out = (float*)d_out;

    int NB = (Nn + BMSK) >> BSH;   // 256-node buckets (391)

    // ws layout (4B words):
    // xwh [N*16] | dis [N] | cursor [N+1] | M [NB*PBLK] | total [NB] |
    // base [NB+1] | staging [E] | esr [E]
    size_t o = 0;
    __half*   xwh     = (__half*)d_ws;       o += (size_t)Nn * (F_OUT / 2);
    float*    dis     = (float*)d_ws + o;    o += Nn;
    int*      cursor  = (int*)d_ws + o;      o += Nn + 1;
    int*      M       = (int*)d_ws + o;      o += (size_t)NB * PBLK;
    int*      total   = (int*)d_ws + o;      o += NB;
    int*      base    = (int*)d_ws + o;      o += NB + 1;
    unsigned* staging = (unsigned*)d_ws + o; o += E_;
    int*      esr     = (int*)d_ws + o;      o += E_;
    bool big_ws = (ws_size >= o * sizeof(float)) && (NB <= MAXB);

    if (big_ws) {
        k_hist<<<PBLK, 256, 0, stream>>>(ei + E_, M, E_, NB);
        k_scanA<<<NB, 256, 0, stream>>>(M, total, NB);
        k_scat1<<<PBLK, 256, 0, stream>>>(ei, M, total, base, staging, E_, NB);
        k_sort2<<<NB, 512, 0, stream>>>(staging, base, esr, dis, cursor, Nn, E_, NB);
        k1_xw<<<(Nn + 127) / 128, 256, 0, stream>>>(x, W, u, dis, xwh, Nn);
        k_gather<<<(Nn + 63) / 64, 512, 0, stream>>>(esr, cursor, xwh, dis, bias, pa, out, Nn);
    } else {
        // fp32 fallback: xw | Wsc | dis | deg
        size_t o2 = 0;
        float* xw2  = (float*)d_ws;       o2 += (size_t)Nn * F_OUT;
        float* Wsc2 = (float*)d_ws + o2;  o2 += F_OUT * F_IN;
        float* dis2 = (float*)d_ws + o2;  o2 += Nn;
        int*   deg2 = (int*)d_ws + o2;    o2 += Nn;
        hipMemsetAsync(deg2, 0, (size_t)Nn * sizeof(int), stream);
        hipMemsetAsync(d_out, 0, (size_t)Nn * F_OUT * sizeof(float), stream);
        k0_specnorm<<<1, 128, 0, stream>>>(W, u, Wsc2);
        k2_deg<<<(E_ + 255) / 256, 256, 0, stream>>>(ei + E_, deg2, E_);
        k3_dis<<<(Nn + 255) / 256, 256, 0, stream>>>(deg2, dis2, Nn);
        int nT1 = Nn * F_OUT;
        k1_xw_f32<<<(nT1 + 255) / 256, 256, 0, stream>>>(x, Wsc2, dis2, xw2, Nn);
        int nT4 = E_ * F_OUT;
        k4_scatter<<<(nT4 + 255) / 256, 256, 0, stream>>>(ei, xw2, dis2, out, E_);
        k5_epi<<<(nT1 + 255) / 256, 256, 0, stream>>>(xw2, dis2, bias, pa, out, Nn);
    }
}

// Round 11
// 175.224 us; speedup vs baseline: 1.0891x; 1.0072x over previous
//
#include <hip/hip_runtime.h>
#include <hip/hip_fp16.h>

#define F_IN 128
#define F_OUT 32
#define PBLK 512   // phase-1 partition blocks
#define BSH 8      // 256 nodes per bucket
#define BMSK 255
#define MAXB 512   // max buckets (N <= 131072)
#define SCAP 12288 // LDS sort capacity (edges) per bucket

// ============ L1: k_hist — per-partition bucket histogram -> M[b][p] ======
__global__ __launch_bounds__(256) void k_hist(const int* __restrict__ col,
                                              int* __restrict__ M, int E_, int NB) {
    __shared__ int h[MAXB];
    int p = blockIdx.x, t = threadIdx.x;
    for (int b = t; b < NB; b += 256) h[b] = 0;
    __syncthreads();
    int epb = (E_ + PBLK - 1) / PBLK;
    int e0 = p * epb, e1 = min(e0 + epb, E_);
    for (int e = e0 + t; e < e1; e += 256)
        atomicAdd(&h[col[e] >> BSH], 1);            // LDS atomic
    __syncthreads();
    for (int b = t; b < NB; b += 256) M[(size_t)b * PBLK + p] = h[b];
}

// ============ L2: k_scanA — per-bucket exclusive scan over P=512 parts ====
__global__ __launch_bounds__(256) void k_scanA(int* __restrict__ M,
                                               int* __restrict__ total, int NB) {
    __shared__ int sd[256];
    int b = blockIdx.x, t = threadIdx.x;
    int v0 = M[(size_t)b * PBLK + 2 * t];
    int v1 = M[(size_t)b * PBLK + 2 * t + 1];
    int s = v0 + v1;
    sd[t] = s;
    __syncthreads();
    for (int o = 1; o < 256; o <<= 1) {
        int u = (t >= o) ? sd[t - o] : 0;
        __syncthreads();
        sd[t] += u;
        __syncthreads();
    }
    int cb = sd[t] - s;
    M[(size_t)b * PBLK + 2 * t]     = cb;
    M[(size_t)b * PBLK + 2 * t + 1] = cb + v0;
    if (t == 255) total[b] = sd[255];
}

// ============ L3: k_scat1 — redundant base-scan + partition scatter =======
__global__ __launch_bounds__(256) void k_scat1(
    const int* __restrict__ ei, const int* __restrict__ M,
    const int* __restrict__ total, int* __restrict__ base,
    unsigned* __restrict__ staging, int E_, int NB) {
    __shared__ int scur[MAXB];
    __shared__ int sd[256];
    int p = blockIdx.x, t = threadIdx.x;
    int C = (NB + 255) >> 8;   // <= 2
    int vals[2];
    int run = 0;
    for (int j = 0; j < C; ++j) {
        int b = t * C + j;
        int v = (b < NB) ? total[b] : 0;
        vals[j] = run;
        run += v;
    }
    int tsum = run;
    sd[t] = tsum;
    __syncthreads();
    for (int o = 1; o < 256; o <<= 1) {
        int u = (t >= o) ? sd[t - o] : 0;
        __syncthreads();
        sd[t] += u;
        __syncthreads();
    }
    int cb = sd[t] - tsum;
    for (int j = 0; j < C; ++j) {
        int b = t * C + j;
        if (b < NB) {
            int sb = cb + vals[j];
            scur[b] = sb + M[(size_t)b * PBLK + p];
            if (p == 0) base[b] = sb;
        }
    }
    if (p == 0 && t == 255) base[NB] = sd[255];  // == E
    __syncthreads();
    int epb = (E_ + PBLK - 1) / PBLK;
    int e0 = p * epb, e1 = min(e0 + epb, E_);
    const int* col = ei + E_;
    for (int e = e0 + t; e < e1; e += 256) {
        int c = col[e];
        int r = ei[e];
        int pos = atomicAdd(&scur[c >> BSH], 1);   // LDS atomic (block-private)
        staging[pos] = ((unsigned)r << BSH) | (unsigned)(c & BMSK);
    }
}

// ============ L4: k_deg — per-bucket degree -> dis + cursor (no esr) ======
__global__ __launch_bounds__(512) void k_deg(
    const unsigned* __restrict__ staging, const int* __restrict__ base,
    float* __restrict__ dis, int* __restrict__ cursor, int Nn, int E_, int NB) {
    __shared__ int hist[256];
    __shared__ int sd[256];
    int b = blockIdx.x, t = threadIdx.x;
    int nb0 = b << BSH;
    int nc = min(1 << BSH, Nn - nb0);
    if (t < 256) hist[t] = 0;
    __syncthreads();
    int s0 = base[b], s1 = base[b + 1];
    for (int j = s0 + t; j < s1; j += 512)
        atomicAdd(&hist[staging[j] & BMSK], 1);    // LDS atomic
    __syncthreads();
    int h = 0;
    if (t < 256) {
        h = hist[t];
        if (t < nc) dis[nb0 + t] = rsqrtf((float)h + 1.0f);
        sd[t] = h;
    }
    __syncthreads();
    for (int o = 1; o < 256; o <<= 1) {
        int u = 0;
        if (t < 256 && t >= o) u = sd[t - o];
        __syncthreads();
        if (t < 256) sd[t] += u;
        __syncthreads();
    }
    if (t < 256 && t < nc) cursor[nb0 + t] = s0 + sd[t] - h;
    if (b == NB - 1 && t == 0) cursor[Nn] = E_;
}

// ============ L5: k1_xw — fused specnorm + matmul, xwh = f16(xW^T * dis) ==
__global__ __launch_bounds__(256) void k1_xw(
    const float* __restrict__ x, const float* __restrict__ W,
    const float* __restrict__ u, const float* __restrict__ dis,
    __half* __restrict__ xwh, int Nn) {
    __shared__ float xs[128 * 65];
    __shared__ float wt[128 * 32];
    __shared__ float sv[F_IN];
    __shared__ float sr[F_IN];
    __shared__ float ssc;
    int t = threadIdx.x;

    // ---- redundant spectral norm (per block; W is 16 KB, L2-hot) ----
    if (t < F_IN) {
        float a = 0.f;
        for (int i = 0; i < F_OUT; ++i) a += W[i * F_IN + t] * u[i];
        sv[t] = a; sr[t] = a * a;
    }
    __syncthreads();
    for (int o = 64; o > 0; o >>= 1) {
        if (t < o) sr[t] += sr[t + o];
        __syncthreads();
    }
    if (t == 0) ssc = 1.0f / fmaxf(sqrtf(sr[0]), 1e-12f);
    __syncthreads();
    if (t < F_IN) sv[t] *= ssc;
    __syncthreads();
    if (t < F_OUT) {
        float a = 0.f;
        for (int j = 0; j < F_IN; ++j) a += W[t * F_IN + j] * sv[j];
        sr[t] = a * a;
    }
    __syncthreads();
    for (int o = 16; o > 0; o >>= 1) {
        if (t < o) sr[t] += sr[t + o];
        __syncthreads();
    }
    if (t == 0) ssc = 1.0f / fmaxf(sqrtf(sr[0]), 1e-30f);  // 1/sigma
    __syncthreads();
    float is = ssc;

    // ---- matmul tile ----
    int rbase = blockIdx.x * 128;
    {
        int f = t >> 3;
        int kb = 16 * (t & 7);
        const float4* wrow = (const float4*)(W + (size_t)f * F_IN + kb);
#pragma unroll
        for (int j = 0; j < 4; ++j) {
            float4 w = wrow[j];
            int k = kb + 4 * j;
            wt[(k + 0) * 32 + f] = w.x * is;
            wt[(k + 1) * 32 + f] = w.y * is;
            wt[(k + 2) * 32 + f] = w.z * is;
            wt[(k + 3) * 32 + f] = w.w * is;
        }
    }

    int r0 = (t >> 3) * 4;
    int f0 = (t & 7) * 4;
    float4 acc0 = {0, 0, 0, 0}, acc1 = {0, 0, 0, 0};
    float4 acc2 = {0, 0, 0, 0}, acc3 = {0, 0, 0, 0};
    const float4* wt4 = (const float4*)wt;
    int fq = f0 >> 2;

    for (int kc = 0; kc < 2; ++kc) {
        __syncthreads();
        {
            int rr = t >> 4;
            int k0 = 4 * (t & 15);
#pragma unroll
            for (int pi = 0; pi < 8; ++pi) {
                int r = pi * 16 + rr;
                int grow = rbase + r;
                if (grow >= Nn) grow = Nn - 1;
                float4 v = *(const float4*)(x + (size_t)grow * F_IN + kc * 64 + k0);
                xs[r * 65 + k0 + 0] = v.x;
                xs[r * 65 + k0 + 1] = v.y;
                xs[r * 65 + k0 + 2] = v.z;
                xs[r * 65 + k0 + 3] = v.w;
            }
        }
        __syncthreads();
#pragma unroll 4
        for (int kk = 0; kk < 64; ++kk) {
            int k = kc * 64 + kk;
            float4 w = wt4[k * 8 + fq];
            float x0 = xs[(r0 + 0) * 65 + kk];
            float x1 = xs[(r0 + 1) * 65 + kk];
            float x2 = xs[(r0 + 2) * 65 + kk];
            float x3 = xs[(r0 + 3) * 65 + kk];
            acc0.x += x0 * w.x; acc0.y += x0 * w.y; acc0.z += x0 * w.z; acc0.w += x0 * w.w;
            acc1.x += x1 * w.x; acc1.y += x1 * w.y; acc1.z += x1 * w.z; acc1.w += x1 * w.w;
            acc2.x += x2 * w.x; acc2.y += x2 * w.y; acc2.z += x2 * w.z; acc2.w += x2 * w.w;
            acc3.x += x3 * w.x; acc3.y += x3 * w.y; acc3.z += x3 * w.z; acc3.w += x3 * w.w;
        }
    }
    int g0 = rbase + r0;
#pragma unroll
    for (int q = 0; q < 4; ++q) {
        int g = g0 + q;
        if (g < Nn) {
            float d = dis[g];
            float4 a = (q == 0) ? acc0 : (q == 1) ? acc1 : (q == 2) ? acc2 : acc3;
            ushort4 s;
            s.x = __half_as_ushort(__float2half(a.x * d));
            s.y = __half_as_ushort(__float2half(a.y * d));
            s.z = __half_as_ushort(__float2half(a.z * d));
            s.w = __half_as_ushort(__float2half(a.w * d));
            *(ushort4*)(xwh + (size_t)g * F_OUT + f0) = s;
        }
    }
}

// ============ L6: k_sortgather — LDS sort + register gather, no esr =======
__device__ __forceinline__ void acc_row(const __half* xws, int r, int f4, float4& acc) {
    uint2 raw = *((const uint2*)(xws + (size_t)r * F_OUT) + f4);
    __half2 h0 = *reinterpret_cast<__half2*>(&raw.x);
    __half2 h1 = *reinterpret_cast<__half2*>(&raw.y);
    float2 fa = __half22float2(h0);
    float2 fb = __half22float2(h1);
    acc.x += fa.x; acc.y += fa.y; acc.z += fb.x; acc.w += fb.y;
}

__global__ __launch_bounds__(512) void k_sortgather(
    const unsigned* __restrict__ staging, const int* __restrict__ base,
    const int* __restrict__ cursor, const __half* __restrict__ xws,
    const float* __restrict__ bias, const float* __restrict__ pa,
    float* __restrict__ out, int* __restrict__ esr, int Nn, int E_, int NB) {
    __shared__ int sidx[SCAP];   // 48 KB sorted row indices
    __shared__ int cst[257];     // local start offsets
    __shared__ int lcur[256];
    int b = blockIdx.x, t = threadIdx.x;
    int nb0 = b << BSH;
    int nc = min(1 << BSH, Nn - nb0);
    int s0 = base[b], s1 = base[b + 1];
    int seg = s1 - s0;
    if (t < 256) {
        int v = (t < nc) ? (cursor[nb0 + t] - s0) : seg;
        cst[t] = v;
        lcur[t] = v;
    }
    if (t == 0) cst[256] = seg;
    __syncthreads();

    if (seg <= SCAP) {
        // sort into LDS
        for (int j = s0 + t; j < s1; j += 512) {
            unsigned v = staging[j];
            int p = atomicAdd(&lcur[v & BMSK], 1);   // LDS atomic
            sidx[p] = (int)(v >> BSH);
        }
        __syncthreads();
        // gather from LDS indices: 64 groups x 8 lanes, 4 nodes/group
        int g = t >> 3, l = t & 7;
        float aslope = pa[0];
        float4 bi = *((const float4*)bias + l);
        for (int n = g; n < nc; n += 64) {
            int c0 = cst[n], c1 = cst[n + 1];
            float4 acc = {0, 0, 0, 0};
            int j = c0;
            for (; j + 8 <= c1; j += 8) {
                int r0 = sidx[j + 0], r1 = sidx[j + 1];
                int r2 = sidx[j + 2], r3 = sidx[j + 3];
                int r4 = sidx[j + 4], r5 = sidx[j + 5];
                int r6 = sidx[j + 6], r7 = sidx[j + 7];
                acc_row(xws, r0, l, acc); acc_row(xws, r1, l, acc);
                acc_row(xws, r2, l, acc); acc_row(xws, r3, l, acc);
                acc_row(xws, r4, l, acc); acc_row(xws, r5, l, acc);
                acc_row(xws, r6, l, acc); acc_row(xws, r7, l, acc);
            }
            for (; j < c1; ++j) acc_row(xws, sidx[j], l, acc);
            float dc = rsqrtf((float)(c1 - c0) + 1.0f);
            float4 self;
            {
                uint2 raw = *((const uint2*)(xws + (size_t)(nb0 + n) * F_OUT) + l);
                __half2 h0 = *reinterpret_cast<__half2*>(&raw.x);
                __half2 h1 = *reinterpret_cast<__half2*>(&raw.y);
                float2 fa = __half22float2(h0);
                float2 fb = __half22float2(h1);
                self = make_float4(fa.x, fa.y, fb.x, fb.y);
            }
            float4 o;
            o.x = (acc.x + self.x) * dc + bi.x;
            o.y = (acc.y + self.y) * dc + bi.y;
            o.z = (acc.z + self.z) * dc + bi.z;
            o.w = (acc.w + self.w) * dc + bi.w;
            o.x = (o.x >= 0.f) ? o.x : aslope * o.x;
            o.y = (o.y >= 0.f) ? o.y : aslope * o.y;
            o.z = (o.z >= 0.f) ? o.z : aslope * o.z;
            o.w = (o.w >= 0.f) ? o.w : aslope * o.w;
            *((float4*)(out + (size_t)(nb0 + n) * F_OUT) + l) = o;
        }
    } else {
        // spill path: sort to global esr, gather from global
        for (int j = s0 + t; j < s1; j += 512) {
            unsigned v = staging[j];
            int p = atomicAdd(&lcur[v & BMSK], 1);
            esr[s0 + p] = (int)(v >> BSH);
        }
        __syncthreads();
        int g = t >> 3, l = t & 7;
        float aslope = pa[0];
        float4 bi = *((const float4*)bias + l);
        for (int n = g; n < nc; n += 64) {
            int c0 = cst[n], c1 = cst[n + 1];
            float4 acc = {0, 0, 0, 0};
            for (int j = c0; j < c1; ++j) acc_row(xws, esr[s0 + j], l, acc);
            float dc = rsqrtf((float)(c1 - c0) + 1.0f);
            float4 self;
            {
                uint2 raw = *((const uint2*)(xws + (size_t)(nb0 + n) * F_OUT) + l);
                __half2 h0 = *reinterpret_cast<__half2*>(&raw.x);
                __half2 h1 = *reinterpret_cast<__half2*>(&raw.y);
                float2 fa = __half22float2(h0);
                float2 fb = __half22float2(h1);
                self = make_float4(fa.x, fa.y, fb.x, fb.y);
            }
            float4 o;
            o.x = (acc.x + self.x) * dc + bi.x;
            o.y = (acc.y + self.y) * dc + bi.y;
            o.z = (acc.z + self.z) * dc + bi.z;
            o.w = (acc.w + self.w) * dc + bi.w;
            o.x = (o.x >= 0.f) ? o.x : aslope * o.x;
            o.y = (o.y >= 0.f) ? o.y : aslope * o.y;
            o.z = (o.z >= 0.f) ? o.z : aslope * o.z;
            o.w = (o.w >= 0.f) ? o.w : aslope * o.w;
            *((float4*)(out + (size_t)(nb0 + n) * F_OUT) + l) = o;
        }
    }
}

// =================== Fallback path (small ws): atomic scatter ============
__global__ void k0_specnorm(const float* __restrict__ W, const float* __restrict__ u,
                            float* __restrict__ Wsc) {
    __shared__ float v[F_IN];
    __shared__ float red[F_IN];
    __shared__ float scal;
    int t = threadIdx.x;
    float acc = 0.f;
    for (int i = 0; i < F_OUT; ++i) acc += W[i * F_IN + t] * u[i];
    v[t] = acc; red[t] = acc * acc;
    __syncthreads();
    if (t == 0) {
        float s = 0.f;
        for (int i = 0; i < F_IN; ++i) s += red[i];
        scal = 1.0f / fmaxf(sqrtf(s), 1e-12f);
    }
    __syncthreads();
    v[t] *= scal;
    __syncthreads();
    if (t < F_OUT) {
        float a2 = 0.f;
        for (int j = 0; j < F_IN; ++j) a2 += W[t * F_IN + j] * v[j];
        red[t] = a2 * a2;
    }
    __syncthreads();
    if (t == 0) {
        float s = 0.f;
        for (int i = 0; i < F_OUT; ++i) s += red[i];
        scal = 1.0f / fmaxf(sqrtf(s), 1e-30f);
    }
    __syncthreads();
    float is = scal;
    for (int i = 0; i < F_OUT; ++i)
        Wsc[i * F_IN + t] = W[i * F_IN + t] * is;
}

__global__ void k1_xw_f32(const float* __restrict__ x, const float* __restrict__ Wsc,
                          const float* __restrict__ dis, float* __restrict__ xw, int Nn) {
    int id = blockIdx.x * blockDim.x + threadIdx.x;
    if (id >= Nn * F_OUT) return;
    int r = id >> 5, f = id & 31;
    const float4* x4 = (const float4*)(x + (size_t)r * F_IN);
    const float4* w4 = (const float4*)(Wsc + (size_t)f * F_IN);
    float acc = 0.f;
#pragma unroll
    for (int k = 0; k < F_IN / 4; ++k) {
        float4 a = x4[k];
        float4 b = w4[k];
        acc += a.x * b.x + a.y * b.y + a.z * b.z + a.w * b.w;
    }
    xw[id] = acc * dis[r];
}

__global__ void k2_deg(const int* __restrict__ col, int* __restrict__ cnt, int E_) {
    int e = blockIdx.x * blockDim.x + threadIdx.x;
    if (e < E_) atomicAdd(&cnt[col[e]], 1);
}

__global__ void k3_dis(const int* __restrict__ cnt, float* __restrict__ dis, int Nn) {
    int i = blockIdx.x * blockDim.x + threadIdx.x;
    if (i < Nn) dis[i] = rsqrtf((float)cnt[i] + 1.0f);
}

__global__ void k4_scatter(const int* __restrict__ ei, const float* __restrict__ xws,
                           const float* __restrict__ dis, float* __restrict__ out, int E_) {
    int id = blockIdx.x * blockDim.x + threadIdx.x;
    if (id >= E_ * F_OUT) return;
    int e = id >> 5, f = id & 31;
    int r = ei[e];
    int c = ei[E_ + e];
    atomicAdd(&out[(size_t)c * F_OUT + f], xws[(size_t)r * F_OUT + f] * dis[c]);
}

__global__ void k5_epi(const float* __restrict__ xws, const float* __restrict__ dis,
                       const float* __restrict__ bias, const float* __restrict__ pa,
                       float* __restrict__ out, int Nn) {
    int id = blockIdx.x * blockDim.x + threadIdx.x;
    if (id >= Nn * F_OUT) return;
    int i = id >> 5, f = id & 31;
    float d = dis[i];
    float v = out[id] + xws[id] * d + bias[f];
    float a = pa[0];
    out[id] = (v >= 0.f) ? v : a * v;
}

extern "C" void kernel_launch(void* const* d_in, const int* in_sizes, int n_in,
                              void* d_out, int out_size, void* d_ws, size_t ws_size,
                              hipStream_t stream) {
    const float* x    = (const float*)d_in[0];
    const int*   ei   = (const int*)d_in[1];   // [2,E]: row = ei[0:E], col = ei[E:2E]
    const float* W    = (const float*)d_in[2];
    const float* bias = (const float*)d_in[3];
    const float* pa   = (const float*)d_in[4];
    const float* u    = (const float*)d_in[5];

    int Nn = in_sizes[0] / F_IN;   // 100000
    int E_ = in_sizes[1] / 2;      // 1600000
    float* out = (float*)d_out;

    int NB = (Nn + BMSK) >> BSH;   // 256-node buckets (391)

    // ws layout (4B words):
    // xwh [N*16] | dis [N] | cursor [N+1] | M [NB*PBLK] | total [NB] |
    // base [NB+1] | staging [E] | esr [E] (spill only)
    size_t o = 0;
    __half*   xwh     = (__half*)d_ws;       o += (size_t)Nn * (F_OUT / 2);
    float*    dis     = (float*)d_ws + o;    o += Nn;
    int*      cursor  = (int*)d_ws + o;      o += Nn + 1;
    int*      M       = (int*)d_ws + o;      o += (size_t)NB * PBLK;
    int*      total   = (int*)d_ws + o;      o += NB;
    int*      base    = (int*)d_ws + o;      o += NB + 1;
    unsigned* staging = (unsigned*)d_ws + o; o += E_;
    int*      esr     = (int*)d_ws + o;      o += E_;
    bool big_ws = (ws_size >= o * sizeof(float)) && (NB <= MAXB);

    if (big_ws) {
        k_hist<<<PBLK, 256, 0, stream>>>(ei + E_, M, E_, NB);
        k_scanA<<<NB, 256, 0, stream>>>(M, total, NB);
        k_scat1<<<PBLK, 256, 0, stream>>>(ei, M, total, base, staging, E_, NB);
        k_deg<<<NB, 512, 0, stream>>>(staging, base, dis, cursor, Nn, E_, NB);
        k1_xw<<<(Nn + 127) / 128, 256, 0, stream>>>(x, W, u, dis, xwh, Nn);
        k_sortgather<<<NB, 512, 0, stream>>>(staging, base, cursor, xwh, bias, pa,
                                             out, esr, Nn, E_, NB);
    } else {
        // fp32 fallback: xw | Wsc | dis | deg
        size_t o2 = 0;
        float* xw2  = (float*)d_ws;       o2 += (size_t)Nn * F_OUT;
        float* Wsc2 = (float*)d_ws + o2;  o2 += F_OUT * F_IN;
        float* dis2 = (float*)d_ws + o2;  o2 += Nn;
        int*   deg2 = (int*)d_ws + o2;    o2 += Nn;
        hipMemsetAsync(deg2, 0, (size_t)Nn * sizeof(int), stream);
        hipMemsetAsync(d_out, 0, (size_t)Nn * F_OUT * sizeof(float), stream);
        k0_specnorm<<<1, 128, 0, stream>>>(W, u, Wsc2);
        k2_deg<<<(E_ + 255) / 256, 256, 0, stream>>>(ei + E_, deg2, E_);
        k3_dis<<<(Nn + 255) / 256, 256, 0, stream>>>(deg2, dis2, Nn);
        int nT1 = Nn * F_OUT;
        k1_xw_f32<<<(nT1 + 255) / 256, 256, 0, stream>>>(x, Wsc2, dis2, xw2, Nn);
        int nT4 = E_ * F_OUT;
        k4_scatter<<<(nT4 + 255) / 256, 256, 0, stream>>>(ei, xw2, dis2, out, E_);
        k5_epi<<<(nT1 + 255) / 256, 256, 0, stream>>>(xw2, dis2, bias, pa, out, Nn);
    }
}